// Round 9
// baseline (233.840 us; speedup 1.0000x reference)
//
#include <hip/hip_runtime.h>
#include <hip/hip_bf16.h>

// Round 9: round-8 design with the f0 bug fixed (640-task phases were gated
// by `if (t<640)` in a 512-thread block -> atoms 12-15 got uninitialized
// c/h). Those phases now stride. All else identical to round 8:
//  - k_prep: pair geometry (ivcu), Wmf B-frag transform, barrier init.
//  - k_all: 256 blocks x 512 thr, block=(mol,sib)=16 atoms; f0 + 5 steps;
//    per-molecule device-scope atomic barriers; cross-sibling x/h/x0 via
//    agent-scope atomics; MFMA env-GEMM identical to rounds 4-7 (verified).

#define DEG 32
#define NA 4096
#define NP 131072

typedef __hip_bfloat16 bf16;
typedef __attribute__((ext_vector_type(8))) short short8v;
typedef __attribute__((ext_vector_type(4))) float f32x4;

#define Z0F 16.27906976744186f
#define DZ  1.0526315789473684f

__device__ __forceinline__ float frcp(float x){ return __builtin_amdgcn_rcpf(x); }
__device__ __forceinline__ float sigmoid_f(float x){ return frcp(1.f + __expf(-x)); }
__device__ __forceinline__ float tanh_f(float x){ return 1.f - 2.f*frcp(__expf(2.f*x)+1.f); }
__device__ __forceinline__ float softplus_f(float x){ return fmaxf(x,0.f) + __logf(1.f + __expf(-fabsf(x))); }
__device__ __forceinline__ unsigned bf16pack(float lo, float hi){
  unsigned ul = __float_as_uint(lo), uh = __float_as_uint(hi);
  unsigned rl = (ul + 0x7fffu + ((ul>>16)&1u)) >> 16;
  unsigned rh = (uh + 0x7fffu + ((uh>>16)&1u)) & 0xffff0000u;
  return rl | rh;
}
// agent-scope (LLC-coherent) cross-block ld/st
__device__ __forceinline__ unsigned ga_ld(const unsigned* p){
  return __hip_atomic_load(p, __ATOMIC_RELAXED, __HIP_MEMORY_SCOPE_AGENT); }
__device__ __forceinline__ float ga_ldf(const float* p){
  return __hip_atomic_load(p, __ATOMIC_RELAXED, __HIP_MEMORY_SCOPE_AGENT); }
__device__ __forceinline__ void ga_st(unsigned* p, unsigned v){
  __hip_atomic_store(p, v, __ATOMIC_RELAXED, __HIP_MEMORY_SCOPE_AGENT); }
__device__ __forceinline__ void ga_stf(float* p, float v){
  __hip_atomic_store(p, v, __ATOMIC_RELAXED, __HIP_MEMORY_SCOPE_AGENT); }

__device__ __forceinline__ void mol_barrier(int* barm, int target){
  __syncthreads();
  if (threadIdx.x==0){
    __threadfence();
    __hip_atomic_fetch_add(barm, 1, __ATOMIC_RELEASE, __HIP_MEMORY_SCOPE_AGENT);
    while (__hip_atomic_load(barm, __ATOMIC_ACQUIRE, __HIP_MEMORY_SCOPE_AGENT) < target)
      __builtin_amdgcn_s_sleep(1);
  }
  __syncthreads();
}

// ---- LDS word offsets (58,528 B) ----
#define P_IVCU 0          // float2[512] = 1024 w (own 16 atoms' pairs)
#define P_NB   1024       // u8[512] = 128 w
#define P_XIN  1152       // [128]
#define P_XHP  1280       // u32[128*20] = 2560 w (x|h bf16 pairs, whole mol)
#define P_C    3840       // [16*20] = 320 w (own c state)
#define P_PRJ  4160       // [16]
#define P_PW1  4176       // [20]
#define R0     4200       // overlay arena (10432 w)
#define F_INDF R0         //   f0: [128*5]=640
#define F_ENV0 (R0+640)   //   f0: [16*100]=1600
#define F_Y0A  (R0+2240)  //   f0: 640
#define F_Y0B  (R0+2880)  //   f0: 640
#define X_WTS  R0         //   xt: 1700 (restaged each step)
#define X_EV1  (R0+1700)  //   xt: 320
#define X_YA   (R0+2020)  //   xt: 320
#define X_YB   (R0+2340)  //   xt: 320
#define SVOFF  R0         //   env: sv[16][652]=10432
#define G_ER   R0         //   gemm: u32[16*436]=6976
#define G_TMP  (R0+6976)  //   gemm: [16*80]=1280
#define G_RED  (R0+8256)  //   lstm: 320
#define G_HT   (R0+8576)  //   lstm: 320 (h, survives to next step)
#define SMEMW  (R0+10432) // 14632 words

// ---------------- prep: pair geometry, W->B-frag, barrier init ----------------
__global__ __launch_bounds__(256) void k_prep(
    const int* __restrict__ pf, const int* __restrict__ ps,
    const float* __restrict__ coord,
    const float* __restrict__ Wint, const float* __restrict__ Wself,
    float2* __restrict__ ivcu_g, bf16* __restrict__ Wmf, int* __restrict__ bar)
{
  int tid = blockIdx.x*256 + threadIdx.x;
  if (tid < NP){
    int i = pf[tid], j = ps[tid];
    float dx = coord[i*3+0]-coord[j*3+0];
    float dy = coord[i*3+1]-coord[j*3+1];
    float dz = coord[i*3+2]-coord[j*3+2];
    float d = sqrtf(dx*dx+dy*dy+dz*dz + 1e-12f);
    float cu = 0.f;
    if (d < 7.5f){ float c = __cosf(d * 0.20943951023931953f); cu = c*c; } // pi/15
    ivcu_g[tid] = make_float2(1.f/d, cu);
  }
  if (tid < 69120){
    int j = tid & 7, l = (tid>>3) & 63, gt = (tid>>9)%5, slab = tid/2560;
    int k = slab*32 + ((l>>4)<<3) + j;
    int g = gt*16 + (l&15);
    float v = 0.f;
    if (k < 800)      v = Wint[k*80+g];
    else if (k < 840) v = Wself[(k-800)*80+g];
    Wmf[tid] = __float2bfloat16(v);
  }
  if (tid < 32) bar[tid] = 0;
}

// ---------------- the whole recurrence ----------------------------------------
__global__ __launch_bounds__(512) void k_all(
    const int* __restrict__ ps, const float2* __restrict__ ivcu_g,
    const int* __restrict__ species, const float* __restrict__ xh,
    const float* __restrict__ xraw,
    const float* __restrict__ h0_iw, const float* __restrict__ h0_sw,
    const float* __restrict__ h0_sb, const float* __restrict__ h0_aw,
    const float* __restrict__ h0_ab,
    const float* __restrict__ h1_iw, const float* __restrict__ h1_sw,
    const float* __restrict__ h1_sb, const float* __restrict__ h1_aw,
    const float* __restrict__ h1_ab,
    const bf16* __restrict__ Wmf, const float* __restrict__ Wb,
    const float* __restrict__ pw0, const float* __restrict__ pw1,
    const float* __restrict__ pb1,
    unsigned* __restrict__ xbg, float* __restrict__ x0g,
    float* __restrict__ outp, int* __restrict__ bar)
{
  __shared__ float smem[SMEMW];
  const int t = threadIdx.x;
  const int mol = blockIdx.x & 31, sib = blockIdx.x >> 5;  // siblings same XCD
  const int nbase = mol*128;
  const int arow0 = sib*16;
  const int abase = nbase + arow0;
  int* barm = bar + mol;
  int barno = 0;

  float2* ivcu_s = (float2*)(smem + P_IVCU);
  unsigned char* nb8 = (unsigned char*)(smem + P_NB);
  float* xin_s = smem + P_XIN;
  unsigned* xhp = (unsigned*)(smem + P_XHP);
  float* c_s = smem + P_C;
  float* prj = smem + P_PRJ;
  float* pw1s = smem + P_PW1;

  // ---- prologue: own pairs' ivcu + nb, pw1
  {
    int pbase = abase*DEG;
    ivcu_s[t] = ivcu_g[pbase + t];
    nb8[t] = (unsigned char)(ps[pbase + t] - nbase);
    if (t < 20) pw1s[t] = pw1[t];
  }
  // ---- f0 (own 16 atoms; indf staged molecule-wide)
  {
    float* indf = smem + F_INDF;
    float* env0 = smem + F_ENV0;
    float* y0a  = smem + F_Y0A;
    float* y0b  = smem + F_Y0B;
    if (t < 128){
      int sp = species[nbase+t];
      indf[t*5+0] = (sp==1)?1.f:0.f;
      indf[t*5+1] = (sp==8)?1.f:0.f;
      indf[t*5+2] = xh[(nbase+t)*3+0];
      indf[t*5+3] = xh[(nbase+t)*3+1];
      indf[t*5+4] = xh[(nbase+t)*3+2];
    }
    __syncthreads();
    if (t < 16){
      int row = arow0 + t;
      prj[t] = pb1[0] + indf[row*5+0]*pw0[0] + indf[row*5+1]*pw0[1]
             + indf[row*5+2]*pw0[2] + indf[row*5+3]*pw0[3] + indf[row*5+4]*pw0[4];
    }
    for(int task=t; task<1600; task+=512){
      int a = task/100, e = task%100, s = e/5, f = e%5;
      const float2* ivr = ivcu_s + a*32;
      const unsigned char* nbr = nb8 + a*32;
      float sz = (float)s*DZ, acc = 0.f;
      for(int k=0;k<32;k++){
        float2 vc = ivr[k];
        float z = (vc.x-0.2f)*Z0F - sz;
        acc += vc.y*__expf(-0.5f*z*z)*indf[nbr[k]*5+f];
      }
      env0[a*100+e] = acc;
    }
    __syncthreads();
    for(int task=t; task<640; task+=512){           // FIX: was if(t<640)
      int a=task/40, o=task%40, row=arow0+a;
      float acc = h0_sb[o];
      #pragma unroll
      for(int f=0;f<5;f++) acc += indf[row*5+f]*h0_sw[f*40+o];
      for(int e=0;e<100;e++) acc += env0[a*100+e]*h0_iw[e*40+o];
      y0a[a*40+o] = softplus_f(acc);
    }
    __syncthreads();
    float* cur = y0a; float* nxt = y0b;
    for(int l=0;l<3;l++){
      for(int task=t; task<640; task+=512){         // FIX: was if(t<640)
        int a=task/40, o=task%40;
        float acc = h0_ab[l*40+o];
        for(int f=0;f<40;f++) acc += cur[a*40+f]*h0_aw[l*1600+f*40+o];
        nxt[a*40+o] = softplus_f(acc);
      }
      __syncthreads();
      float* tswap=cur; cur=nxt; nxt=tswap;
    }
    // result in y0b: chain y0a->y0b->y0a->y0b
    if (t < 320){ int a=t/20,u=t%20; c_s[a*20+u] = y0b[a*40+u]; }
    if (t < 160){ int a=t/10,p=t%10;
      ga_st(&xbg[(abase+a)*20+10+p], bf16pack(y0b[a*40+20+2*p], y0b[a*40+21+2*p])); }
  }
  mol_barrier(barm, 8*(++barno));

  // ---- 5 recurrence steps
  for(int step=0; step<5; ++step){
    int use_raw = (step<2)?1:0, col = (step<2)? step : 0;
    int out_col = (step>=2)? (step-2) : -1;
    float* wts = smem + X_WTS;
    float* env1 = smem + X_EV1;
    float* yA = smem + X_YA;
    float* yB = smem + X_YB;

    // deferred h write from previous step (race-free: peers read post-barA)
    if (step > 0 && t < 160){
      int a=t/10, p=t%10;
      const float* ht = smem + G_HT;
      ga_st(&xbg[(abase+a)*20+10+p], bf16pack(ht[a*20+2*p], ht[a*20+2*p+1]));
    }
    // stage xt weights + xin (whole molecule)
    for(int i=t;i<1700;i+=512){
      float v;
      if(i<400){ int o=i/20,s=i%20; v=h1_iw[s*20+o]; }
      else if(i<420) v=h1_sw[i-400];
      else if(i<440) v=h1_sb[i-420];
      else if(i<1640){ int q=i-440,l=q/400,rem=q%400,o=rem/20,f=rem%20; v=h1_aw[l*400+f*20+o]; }
      else v=h1_ab[i-1640];
      wts[i]=v;
    }
    if (t < 128)
      xin_s[t] = use_raw ? xraw[(nbase+t)*2+col] : ga_ldf(&x0g[nbase+t]);
    __syncthreads();

    // xt env (own 16 atoms)
    if (t < 320){
      int a=t/20, s=t%20;
      float sz = (float)s*DZ, acc = 0.f;
      const float2* ivr = ivcu_s + a*32;
      const unsigned char* nbr = nb8 + a*32;
      for(int k=0;k<32;k++){
        float2 vc = ivr[k];
        float z = (vc.x-0.2f)*Z0F - sz;
        acc += vc.y*__expf(-0.5f*z*z)*xin_s[nbr[k]];
      }
      env1[a*20+s] = acc;
    }
    __syncthreads();
    if (t < 320){
      int a=t/20, o=t%20;
      float xs = xin_s[arow0+a];
      float acc = wts[420+o] + xs*wts[400+o];
      #pragma unroll
      for(int s=0;s<20;s++) acc += env1[a*20+s]*wts[o*20+s];
      yA[a*20+o] = softplus_f(acc);
    }
    __syncthreads();
    #pragma unroll
    for(int L=0;L<2;L++){
      const float* src = (L==0)? yA : yB;
      float* dst = (L==0)? yB : yA;
      if (t < 320){
        int a=t/20, o=t%20;
        float acc = wts[1640+L*20+o];
        #pragma unroll
        for(int f=0;f<20;f++) acc += src[a*20+f]*wts[440+L*400+o*20+f];
        dst[a*20+o] = softplus_f(acc);
      }
      __syncthreads();
    }
    if (t < 160){   // L2 -> x-pairs to global
      int a=t/10, p=t%10, o0=2*p, o1=2*p+1;
      float a0 = wts[1640+40+o0], a1 = wts[1640+40+o1];
      const float* wA = wts + 440 + 800 + o0*20;
      const float* wB = wA + 20;
      const float* sr = yA + a*20;
      #pragma unroll
      for(int f=0;f<20;f++){ a0 += sr[f]*wA[f]; a1 += sr[f]*wB[f]; }
      ga_st(&xbg[(abase+a)*20+p], bf16pack(softplus_f(a0), softplus_f(a1)));
    }
    mol_barrier(barm, 8*(++barno));           // barrier A

    // stage whole molecule's x|h pairs
    for(int i=t;i<2560;i+=512) xhp[i] = ga_ld(&xbg[nbase*20 + i]);
    __syncthreads();

    // sv tile (own 16 atoms), all 512 threads: (a,k)
    {
      float* sv = smem + SVOFF;
      int a = t>>5, k = t&31;
      float2 vc = ivcu_s[a*32+k];
      float z = (vc.x-0.2f)*Z0F, cu = vc.y;
      float* svr = sv + a*652 + k*20;
      #pragma unroll
      for(int s=0;s<20;s++){ svr[s] = cu*__expf(-0.5f*z*z); z -= DZ; }
    }
    __syncthreads();

    // env accumulate (a,f2)
    float accE[20][2]; unsigned selfp = 0;
    if (t < 320){
      int a=t/20, f2=t%20;
      #pragma unroll
      for(int s=0;s<20;s++){ accE[s][0]=0.f; accE[s][1]=0.f; }
      const float* svr = smem + SVOFF + a*652;
      const unsigned char* nbr = nb8 + a*32;
      for(int k=0;k<32;k++){
        unsigned xp = xhp[nbr[k]*20 + f2];
        float xlo = __uint_as_float(xp<<16);
        float xhi = __uint_as_float(xp & 0xffff0000u);
        const float4* sq = (const float4*)(svr + k*20);
        float4 q0=sq[0],q1=sq[1],q2=sq[2],q3=sq[3],q4=sq[4];
        float sv[20]={q0.x,q0.y,q0.z,q0.w, q1.x,q1.y,q1.z,q1.w,
                      q2.x,q2.y,q2.z,q2.w, q3.x,q3.y,q3.z,q3.w,
                      q4.x,q4.y,q4.z,q4.w};
        #pragma unroll
        for(int s=0;s<20;s++){ accE[s][0] += sv[s]*xlo; accE[s][1] += sv[s]*xhi; }
      }
      selfp = xhp[(arow0+a)*20 + f2];
    }
    __syncthreads();        // sv dead; er overlays
    unsigned* er = (unsigned*)(smem + G_ER);
    if (t < 320){
      int a=t/20, f2=t%20;
      unsigned* e = er + a*436;
      #pragma unroll
      for(int s=0;s<20;s++) e[s*20+f2] = bf16pack(accE[s][0], accE[s][1]);
      e[400+f2] = selfp;
    }
    if (t < 256) er[(t>>4)*436 + 420 + (t&15)] = 0u;
    __syncthreads();

    // MFMA GEMM K=864 (verified r4-r7)
    float* tmp_s = smem + G_TMP;
    if (t < 320){
      int wv = t >> 6, l = t & 63;
      f32x4 cacc = {0.f,0.f,0.f,0.f};
      const unsigned* abase_p = er + (l & 15)*436 + ((l>>4)<<2);
      const short8v* bptr = (const short8v*)Wmf + (wv*64 + l);
      #pragma unroll 3
      for(int slab=0; slab<27; ++slab){
        short8v av = *(const short8v*)(abase_p + slab*16);
        short8v bv = bptr[slab*320];
        cacc = __builtin_amdgcn_mfma_f32_16x16x32_bf16(av, bv, cacc, 0,0,0);
      }
      int g = wv*16 + (l & 15);
      float wb = Wb[g];
      int r0 = (l>>4)*4;
      #pragma unroll
      for(int r=0;r<4;r++) tmp_s[(r0+r)*80 + g] = cacc[r] + wb;
    }
    __syncthreads();

    // LSTM + projection
    float* red = smem + G_RED;
    float* ht  = smem + G_HT;
    if (t < 320){
      int a=t/20, u=t%20;
      float4 tv = *(const float4*)(tmp_s + a*80 + u*4);
      float cold = c_s[a*20+u];
      float cnew = sigmoid_f(tv.y)*cold + sigmoid_f(tv.x)*tanh_f(tv.z);
      float og   = sigmoid_f(tv.w);
      c_s[a*20+u] = cnew;
      ht[a*20+u]  = og*tanh_f(cnew);
      red[a*20+u] = og*pw1s[u];
    }
    __syncthreads();
    if (t < 16){
      float accx = prj[t];
      #pragma unroll
      for(int u=0;u<20;u++) accx += red[t*20+u];
      ga_stf(&x0g[abase+t], accx);
      if (out_col >= 0) outp[(abase+t)*3+out_col] = accx;
    }
    mol_barrier(barm, 8*(++barno));           // barrier B
  }
}

extern "C" void kernel_launch(void* const* d_in, const int* in_sizes, int n_in,
                              void* d_out, int out_size, void* d_ws, size_t ws_size,
                              hipStream_t stream)
{
  const int*   species = (const int*)  d_in[0];
  const float* coord   = (const float*)d_in[1];
  const float* xh      = (const float*)d_in[2];
  const float* xraw    = (const float*)d_in[3];
  const int*   pf      = (const int*)  d_in[4];
  const int*   ps      = (const int*)  d_in[5];
  const float* h0_intw = (const float*)d_in[6];
  const float* h0_sw   = (const float*)d_in[7];
  const float* h0_sb   = (const float*)d_in[8];
  const float* h0_aw   = (const float*)d_in[9];
  const float* h0_ab   = (const float*)d_in[10];
  const float* h1_intw = (const float*)d_in[11];
  const float* h1_sw   = (const float*)d_in[12];
  const float* h1_sb   = (const float*)d_in[13];
  const float* h1_aw   = (const float*)d_in[14];
  const float* h1_ab   = (const float*)d_in[15];
  const float* W_intw  = (const float*)d_in[16];
  const float* W_sw    = (const float*)d_in[17];
  const float* W_sb    = (const float*)d_in[18];
  const float* pw0     = (const float*)d_in[19];
  const float* pw1     = (const float*)d_in[20];
  const float* pb1     = (const float*)d_in[21];
  float* outp = (float*)d_out;

  float* w = (float*)d_ws;
  float2* ivcu_g = (float2*)w;  w += 2*NP;        // 1MB
  unsigned* xbg  = (unsigned*)w; w += NA*20;      // x|h bf16 pairs
  float* x0g = w;  w += NA;
  int* bar   = (int*)w; w += 32;
  bf16* Wmf  = (bf16*)w;                          // 69120 bf16

  k_prep<<<512,256,0,stream>>>(pf,ps,coord,W_intw,W_sw, ivcu_g,Wmf,bar);
  k_all<<<256,512,0,stream>>>(ps, ivcu_g, species, xh, xraw,
                              h0_intw,h0_sw,h0_sb,h0_aw,h0_ab,
                              h1_intw,h1_sw,h1_sb,h1_aw,h1_ab,
                              Wmf, W_sb, pw0, pw1, pb1,
                              xbg, x0g, outp, bar);
}

// Round 10
// 140.146 us; speedup vs baseline: 1.6685x; 1.6685x over previous
//
#include <hip/hip_runtime.h>
#include <hip/hip_bf16.h>

// Round 10: persistent-molecule design, cheap barriers.
//  - mol_barrier: RELAXED agent atomics only (no __threadfence, no acquire
//    spin): all cross-block data moves via sc1 (LLC-coherent) atomic ld/st,
//    and __syncthreads drains vmcnt(0) before the counter bump.
//  - 1 barrier/step (6 total, was 11): x_t recomputed molecule-wide per block
//    (round-7-verified code); only h and x0 cross blocks, parity
//    double-buffered to kill the fast-writer/slow-reader race.
//  - f0 / sv / env-accum / MFMA GEMM / LSTM verbatim from verified r7/r9.

#define DEG 32
#define NA 4096
#define NP 131072

typedef __hip_bfloat16 bf16;
typedef __attribute__((ext_vector_type(8))) short short8v;
typedef __attribute__((ext_vector_type(4))) float f32x4;

#define Z0F 16.27906976744186f
#define DZ  1.0526315789473684f

__device__ __forceinline__ float frcp(float x){ return __builtin_amdgcn_rcpf(x); }
__device__ __forceinline__ float sigmoid_f(float x){ return frcp(1.f + __expf(-x)); }
__device__ __forceinline__ float tanh_f(float x){ return 1.f - 2.f*frcp(__expf(2.f*x)+1.f); }
__device__ __forceinline__ float softplus_f(float x){ return fmaxf(x,0.f) + __logf(1.f + __expf(-fabsf(x))); }
__device__ __forceinline__ unsigned bf16pack(float lo, float hi){
  unsigned ul = __float_as_uint(lo), uh = __float_as_uint(hi);
  unsigned rl = (ul + 0x7fffu + ((ul>>16)&1u)) >> 16;
  unsigned rh = (uh + 0x7fffu + ((uh>>16)&1u)) & 0xffff0000u;
  return rl | rh;
}
// agent-scope (LLC-coherent, sc1 cache-bypassing) cross-block ld/st
__device__ __forceinline__ unsigned ga_ld(const unsigned* p){
  return __hip_atomic_load(p, __ATOMIC_RELAXED, __HIP_MEMORY_SCOPE_AGENT); }
__device__ __forceinline__ float ga_ldf(const float* p){
  return __hip_atomic_load(p, __ATOMIC_RELAXED, __HIP_MEMORY_SCOPE_AGENT); }
__device__ __forceinline__ void ga_st(unsigned* p, unsigned v){
  __hip_atomic_store(p, v, __ATOMIC_RELAXED, __HIP_MEMORY_SCOPE_AGENT); }
__device__ __forceinline__ void ga_stf(float* p, float v){
  __hip_atomic_store(p, v, __ATOMIC_RELAXED, __HIP_MEMORY_SCOPE_AGENT); }

// fence-free molecule barrier: __syncthreads implies vmcnt(0) per wave, so all
// sc1 stores are at LLC before the relaxed add; readers use sc1 loads.
__device__ __forceinline__ void mol_barrier(int* barm, int target){
  __syncthreads();
  if (threadIdx.x==0){
    __hip_atomic_fetch_add(barm, 1, __ATOMIC_RELAXED, __HIP_MEMORY_SCOPE_AGENT);
    while (__hip_atomic_load(barm, __ATOMIC_RELAXED, __HIP_MEMORY_SCOPE_AGENT) < target)
      __builtin_amdgcn_s_sleep(2);
  }
  __syncthreads();
}

// ---- LDS word offsets (62,112 B) ----
#define P_IVCU 0          // float2[512] own 16 atoms' pairs
#define P_NB   1024       // u8[4096] whole molecule neighbor idx
#define P_XIN  2048       // [128]
#define P_XHP  2176       // u32[128*20] x|h bf16 pairs (x local, h staged)
#define P_C    4736       // [16*20] own c state
#define P_PRJ  5056       // [16]
#define P_PW1  5072       // [20]
#define R0     5096       // overlay arena (10432 w)
#define F_INDF R0         //   f0: 640
#define F_ENV0 (R0+640)   //   f0: 1600
#define F_Y0A  (R0+2240)  //   f0: 640
#define F_Y0B  (R0+2880)  //   f0: 640
#define X_WTS  R0         //   xt: 1700
#define X_EV1  (R0+1700)  //   xt: 2560 (also yB)
#define X_YA   (R0+4260)  //   xt: 2560
#define SVOFF  R0         //   env: sv[16][652]=10432
#define G_ER   R0         //   gemm: u32[16*436]=6976
#define G_TMP  (R0+6976)  //   gemm: 1280
#define G_RED  (R0+8256)  //   lstm: 320
#define G_HT   (R0+8576)  //   lstm: 320
#define SMEMW  (R0+10432) // 15528 words

// ---------------- prep: pair geometry, W->B-frag, barrier init ----------------
__global__ __launch_bounds__(256) void k_prep(
    const int* __restrict__ pf, const int* __restrict__ ps,
    const float* __restrict__ coord,
    const float* __restrict__ Wint, const float* __restrict__ Wself,
    float2* __restrict__ ivcu_g, bf16* __restrict__ Wmf, int* __restrict__ bar)
{
  int tid = blockIdx.x*256 + threadIdx.x;
  if (tid < NP){
    int i = pf[tid], j = ps[tid];
    float dx = coord[i*3+0]-coord[j*3+0];
    float dy = coord[i*3+1]-coord[j*3+1];
    float dz = coord[i*3+2]-coord[j*3+2];
    float d = sqrtf(dx*dx+dy*dy+dz*dz + 1e-12f);
    float cu = 0.f;
    if (d < 7.5f){ float c = __cosf(d * 0.20943951023931953f); cu = c*c; } // pi/15
    ivcu_g[tid] = make_float2(1.f/d, cu);
  }
  if (tid < 69120){
    int j = tid & 7, l = (tid>>3) & 63, gt = (tid>>9)%5, slab = tid/2560;
    int k = slab*32 + ((l>>4)<<3) + j;
    int g = gt*16 + (l&15);
    float v = 0.f;
    if (k < 800)      v = Wint[k*80+g];
    else if (k < 840) v = Wself[(k-800)*80+g];
    Wmf[tid] = __float2bfloat16(v);
  }
  if (tid < 32) bar[tid] = 0;
}

// ---------------- the whole recurrence ----------------------------------------
__global__ __launch_bounds__(512) void k_all(
    const int* __restrict__ ps, const float2* __restrict__ ivcu_g,
    const int* __restrict__ species, const float* __restrict__ xh,
    const float* __restrict__ xraw,
    const float* __restrict__ h0_iw, const float* __restrict__ h0_sw,
    const float* __restrict__ h0_sb, const float* __restrict__ h0_aw,
    const float* __restrict__ h0_ab,
    const float* __restrict__ h1_iw, const float* __restrict__ h1_sw,
    const float* __restrict__ h1_sb, const float* __restrict__ h1_aw,
    const float* __restrict__ h1_ab,
    const bf16* __restrict__ Wmf, const float* __restrict__ Wb,
    const float* __restrict__ pw0, const float* __restrict__ pw1,
    const float* __restrict__ pb1,
    unsigned* __restrict__ hbuf,   // [2][NA*10] h bf16-pairs, parity-buffered
    float* __restrict__ x0g,       // [2][NA] x0, parity-buffered
    float* __restrict__ outp, int* __restrict__ bar)
{
  __shared__ float smem[SMEMW];
  const int t = threadIdx.x;
  const int mol = blockIdx.x & 31, sib = blockIdx.x >> 5;  // siblings same XCD
  const int nbase = mol*128;
  const int arow0 = sib*16;
  const int abase = nbase + arow0;
  int* barm = bar + mol;
  int barno = 0;

  float2* ivcu_s = (float2*)(smem + P_IVCU);
  unsigned char* nb8 = (unsigned char*)(smem + P_NB);
  float* xin_s = smem + P_XIN;
  unsigned* xhp = (unsigned*)(smem + P_XHP);
  float* c_s = smem + P_C;
  float* prj = smem + P_PRJ;
  float* pw1s = smem + P_PW1;

  // ---- prologue: own pairs' ivcu, whole-mol nb8, pw1
  ivcu_s[t] = ivcu_g[abase*DEG + t];
  for(int i=t;i<4096;i+=512) nb8[i] = (unsigned char)(ps[nbase*DEG + i] - nbase);
  if (t < 20) pw1s[t] = pw1[t];

  // ---- f0 (own 16 atoms; indf staged molecule-wide)
  {
    float* indf = smem + F_INDF;
    float* env0 = smem + F_ENV0;
    float* y0a  = smem + F_Y0A;
    float* y0b  = smem + F_Y0B;
    if (t < 128){
      int sp = species[nbase+t];
      indf[t*5+0] = (sp==1)?1.f:0.f;
      indf[t*5+1] = (sp==8)?1.f:0.f;
      indf[t*5+2] = xh[(nbase+t)*3+0];
      indf[t*5+3] = xh[(nbase+t)*3+1];
      indf[t*5+4] = xh[(nbase+t)*3+2];
    }
    __syncthreads();
    if (t < 16){
      int row = arow0 + t;
      prj[t] = pb1[0] + indf[row*5+0]*pw0[0] + indf[row*5+1]*pw0[1]
             + indf[row*5+2]*pw0[2] + indf[row*5+3]*pw0[3] + indf[row*5+4]*pw0[4];
    }
    for(int task=t; task<1600; task+=512){
      int a = task/100, e = task%100, s = e/5, f = e%5;
      const float2* ivr = ivcu_s + a*32;
      const unsigned char* nbr = nb8 + (arow0+a)*32;
      float sz = (float)s*DZ, acc = 0.f;
      for(int k=0;k<32;k++){
        float2 vc = ivr[k];
        float z = (vc.x-0.2f)*Z0F - sz;
        acc += vc.y*__expf(-0.5f*z*z)*indf[nbr[k]*5+f];
      }
      env0[a*100+e] = acc;
    }
    __syncthreads();
    for(int task=t; task<640; task+=512){
      int a=task/40, o=task%40, row=arow0+a;
      float acc = h0_sb[o];
      #pragma unroll
      for(int f=0;f<5;f++) acc += indf[row*5+f]*h0_sw[f*40+o];
      for(int e=0;e<100;e++) acc += env0[a*100+e]*h0_iw[e*40+o];
      y0a[a*40+o] = softplus_f(acc);
    }
    __syncthreads();
    float* cur = y0a; float* nxt = y0b;
    for(int l=0;l<3;l++){
      for(int task=t; task<640; task+=512){
        int a=task/40, o=task%40;
        float acc = h0_ab[l*40+o];
        for(int f=0;f<40;f++) acc += cur[a*40+f]*h0_aw[l*1600+f*40+o];
        nxt[a*40+o] = softplus_f(acc);
      }
      __syncthreads();
      float* tswap=cur; cur=nxt; nxt=tswap;
    }
    // result in y0b (chain y0a->y0b->y0a->y0b)
    if (t < 320){ int a=t/20,u=t%20; c_s[a*20+u] = y0b[a*40+u]; }
    if (t < 160){ int a=t/10,p=t%10;
      ga_st(&hbuf[NA*10 + (abase+a)*10+p],          // parity 1 (pre-step-0)
            bf16pack(y0b[a*40+20+2*p], y0b[a*40+21+2*p])); }
  }
  mol_barrier(barm, 8*(++barno));

  // ---- 5 recurrence steps, 1 barrier each (last skipped)
  for(int step=0; step<5; ++step){
    int use_raw = (step<2)?1:0, col = (step<2)? step : 0;
    int out_col = (step>=2)? (step-2) : -1;
    int rpar = (step+1)&1, wpar = step&1;
    float* wts = smem + X_WTS;
    float* env1 = smem + X_EV1;
    float* yA = smem + X_YA;

    // stage xt weights, xin (whole molecule), h-half of xhp (prev parity)
    for(int i=t;i<1700;i+=512){
      float v;
      if(i<400){ int o=i/20,s=i%20; v=h1_iw[s*20+o]; }
      else if(i<420) v=h1_sw[i-400];
      else if(i<440) v=h1_sb[i-420];
      else if(i<1640){ int q=i-440,l=q/400,rem=q%400,o=rem/20,f=rem%20; v=h1_aw[l*400+f*20+o]; }
      else v=h1_ab[i-1640];
      wts[i]=v;
    }
    if (t < 128)
      xin_s[t] = use_raw ? xraw[(nbase+t)*2+col] : ga_ldf(&x0g[rpar*NA + nbase + t]);
    for(int i=t;i<1280;i+=512)
      xhp[(i/10)*20 + 10 + (i%10)] = ga_ld(&hbuf[rpar*NA*10 + nbase*10 + i]);
    __syncthreads();

    // xt env1 for all 128 molecule atoms (r7-verified): thread=(r,s0), 5 s each
    {
      int r = t & 127, s0 = t >> 7;
      const float2* ivr = ivcu_g + (nbase + r)*DEG;
      const unsigned char* nbr = nb8 + r*32;
      float acc[5] = {0.f,0.f,0.f,0.f,0.f};
      for(int k=0;k<32;k++){
        float2 vc = ivr[k];
        float xv = xin_s[nbr[k]] * vc.y;
        float z0 = (vc.x-0.2f)*Z0F - (float)s0*DZ;
        #pragma unroll
        for(int i=0;i<5;i++){
          float z = z0 - (float)(4*i)*DZ;
          acc[i] += __expf(-0.5f*z*z) * xv;
        }
      }
      #pragma unroll
      for(int i=0;i<5;i++) env1[r*20 + s0 + 4*i] = acc[i];
    }
    __syncthreads();

    // xt interact (env1 -> yA)
    {
      int r = t&127, o0 = t>>7;
      float e[20];
      { const float4* e4=(const float4*)(env1 + r*20);
        float4 q0=e4[0],q1=e4[1],q2=e4[2],q3=e4[3],q4=e4[4];
        e[0]=q0.x;e[1]=q0.y;e[2]=q0.z;e[3]=q0.w; e[4]=q1.x;e[5]=q1.y;e[6]=q1.z;e[7]=q1.w;
        e[8]=q2.x;e[9]=q2.y;e[10]=q2.z;e[11]=q2.w; e[12]=q3.x;e[13]=q3.y;e[14]=q3.z;e[15]=q3.w;
        e[16]=q4.x;e[17]=q4.y;e[18]=q4.z;e[19]=q4.w; }
      float xr_ = xin_s[r];
      #pragma unroll
      for(int i=0;i<5;i++){
        int o = o0 + 4*i;
        const float* w = wts + o*20;
        float acc = wts[420+o] + xr_*wts[400+o];
        #pragma unroll
        for(int f=0;f<20;f++) acc += e[f]*w[f];
        yA[r*20+o] = softplus_f(acc);
      }
    }
    __syncthreads();

    // layers L0 (yA->env1), L1 (env1->yA)
    #pragma unroll
    for(int L=0;L<2;L++){
      const float* src = (L==0)? yA : env1;
      float* dst       = (L==0)? env1 : yA;
      int r = t&127, o0 = t>>7;
      float e[20];
      { const float4* e4=(const float4*)(src + r*20);
        float4 q0=e4[0],q1=e4[1],q2=e4[2],q3=e4[3],q4=e4[4];
        e[0]=q0.x;e[1]=q0.y;e[2]=q0.z;e[3]=q0.w; e[4]=q1.x;e[5]=q1.y;e[6]=q1.z;e[7]=q1.w;
        e[8]=q2.x;e[9]=q2.y;e[10]=q2.z;e[11]=q2.w; e[12]=q3.x;e[13]=q3.y;e[14]=q3.z;e[15]=q3.w;
        e[16]=q4.x;e[17]=q4.y;e[18]=q4.z;e[19]=q4.w; }
      #pragma unroll
      for(int i=0;i<5;i++){
        int o = o0 + 4*i;
        const float* w = wts + 440 + L*400 + o*20;
        float acc = wts[1640 + L*20 + o];
        #pragma unroll
        for(int f=0;f<20;f++) acc += e[f]*w[f];
        dst[r*20+o] = softplus_f(acc);
      }
      __syncthreads();
    }

    // layer L2 (yA -> xhp x-half, bf16 pairs; x never leaves LDS)
    for(int i=t;i<1280;i+=512){
      int r=i/10, p=i%10;
      float e[20];
      { const float4* e4=(const float4*)(yA + r*20);
        float4 q0=e4[0],q1=e4[1],q2=e4[2],q3=e4[3],q4=e4[4];
        e[0]=q0.x;e[1]=q0.y;e[2]=q0.z;e[3]=q0.w; e[4]=q1.x;e[5]=q1.y;e[6]=q1.z;e[7]=q1.w;
        e[8]=q2.x;e[9]=q2.y;e[10]=q2.z;e[11]=q2.w; e[12]=q3.x;e[13]=q3.y;e[14]=q3.z;e[15]=q3.w;
        e[16]=q4.x;e[17]=q4.y;e[18]=q4.z;e[19]=q4.w; }
      int oA=2*p, oB=2*p+1;
      const float* wA = wts + 1240 + oA*20;   // 440 + 2*400
      const float* wB = wA + 20;
      float a0 = wts[1680+oA], a1 = wts[1680+oB];
      #pragma unroll
      for(int f=0;f<20;f++){ a0 += e[f]*wA[f]; a1 += e[f]*wB[f]; }
      xhp[r*20+p] = bf16pack(softplus_f(a0), softplus_f(a1));
    }
    __syncthreads();

    // sv tile (own 16 atoms); arena: wts/env1/yA now dead
    {
      float* sv = smem + SVOFF;
      int a = t>>5, k = t&31;
      float2 vc = ivcu_s[a*32+k];
      float z = (vc.x-0.2f)*Z0F, cu = vc.y;
      float* svr = sv + a*652 + k*20;
      #pragma unroll
      for(int s=0;s<20;s++){ svr[s] = cu*__expf(-0.5f*z*z); z -= DZ; }
    }
    __syncthreads();

    // env accumulate (a,f2)
    float accE[20][2]; unsigned selfp = 0;
    if (t < 320){
      int a=t/20, f2=t%20;
      #pragma unroll
      for(int s=0;s<20;s++){ accE[s][0]=0.f; accE[s][1]=0.f; }
      const float* svr = smem + SVOFF + a*652;
      const unsigned char* nbr = nb8 + (arow0+a)*32;
      for(int k=0;k<32;k++){
        unsigned xp = xhp[nbr[k]*20 + f2];
        float xlo = __uint_as_float(xp<<16);
        float xhi = __uint_as_float(xp & 0xffff0000u);
        const float4* sq = (const float4*)(svr + k*20);
        float4 q0=sq[0],q1=sq[1],q2=sq[2],q3=sq[3],q4=sq[4];
        float sv[20]={q0.x,q0.y,q0.z,q0.w, q1.x,q1.y,q1.z,q1.w,
                      q2.x,q2.y,q2.z,q2.w, q3.x,q3.y,q3.z,q3.w,
                      q4.x,q4.y,q4.z,q4.w};
        #pragma unroll
        for(int s=0;s<20;s++){ accE[s][0] += sv[s]*xlo; accE[s][1] += sv[s]*xhi; }
      }
      selfp = xhp[(arow0+a)*20 + f2];
    }
    __syncthreads();        // sv dead; er overlays
    unsigned* er = (unsigned*)(smem + G_ER);
    if (t < 320){
      int a=t/20, f2=t%20;
      unsigned* e = er + a*436;
      #pragma unroll
      for(int s=0;s<20;s++) e[s*20+f2] = bf16pack(accE[s][0], accE[s][1]);
      e[400+f2] = selfp;
    }
    if (t < 256) er[(t>>4)*436 + 420 + (t&15)] = 0u;
    __syncthreads();

    // MFMA GEMM K=864 (verified r4-r9)
    float* tmp_s = smem + G_TMP;
    if (t < 320){
      int wv = t >> 6, l = t & 63;
      f32x4 cacc = {0.f,0.f,0.f,0.f};
      const unsigned* abase_p = er + (l & 15)*436 + ((l>>4)<<2);
      const short8v* bptr = (const short8v*)Wmf + (wv*64 + l);
      #pragma unroll 3
      for(int slab=0; slab<27; ++slab){
        short8v av = *(const short8v*)(abase_p + slab*16);
        short8v bv = bptr[slab*320];
        cacc = __builtin_amdgcn_mfma_f32_16x16x32_bf16(av, bv, cacc, 0,0,0);
      }
      int g = wv*16 + (l & 15);
      float wb = Wb[g];
      int r0 = (l>>4)*4;
      #pragma unroll
      for(int r=0;r<4;r++) tmp_s[(r0+r)*80 + g] = cacc[r] + wb;
    }
    __syncthreads();

    // LSTM + h/x0 writes (parity wpar)
    float* red = smem + G_RED;
    float* ht  = smem + G_HT;
    if (t < 320){
      int a=t/20, u=t%20;
      float4 tv = *(const float4*)(tmp_s + a*80 + u*4);
      float cold = c_s[a*20+u];
      float cnew = sigmoid_f(tv.y)*cold + sigmoid_f(tv.x)*tanh_f(tv.z);
      float og   = sigmoid_f(tv.w);
      c_s[a*20+u] = cnew;
      ht[a*20+u]  = og*tanh_f(cnew);
      red[a*20+u] = og*pw1s[u];
    }
    __syncthreads();
    if (t < 160){
      int a=t/10, p=t%10;
      ga_st(&hbuf[wpar*NA*10 + (abase+a)*10+p],
            bf16pack(ht[a*20+2*p], ht[a*20+2*p+1]));
    }
    if (t < 16){
      float accx = prj[t];
      #pragma unroll
      for(int u=0;u<20;u++) accx += red[t*20+u];
      ga_stf(&x0g[wpar*NA + abase + t], accx);
      if (out_col >= 0) outp[(abase+t)*3+out_col] = accx;
    }
    if (step < 4) mol_barrier(barm, 8*(++barno));
  }
}

extern "C" void kernel_launch(void* const* d_in, const int* in_sizes, int n_in,
                              void* d_out, int out_size, void* d_ws, size_t ws_size,
                              hipStream_t stream)
{
  const int*   species = (const int*)  d_in[0];
  const float* coord   = (const float*)d_in[1];
  const float* xh      = (const float*)d_in[2];
  const float* xraw    = (const float*)d_in[3];
  const int*   pf      = (const int*)  d_in[4];
  const int*   ps      = (const int*)  d_in[5];
  const float* h0_intw = (const float*)d_in[6];
  const float* h0_sw   = (const float*)d_in[7];
  const float* h0_sb   = (const float*)d_in[8];
  const float* h0_aw   = (const float*)d_in[9];
  const float* h0_ab   = (const float*)d_in[10];
  const float* h1_intw = (const float*)d_in[11];
  const float* h1_sw   = (const float*)d_in[12];
  const float* h1_sb   = (const float*)d_in[13];
  const float* h1_aw   = (const float*)d_in[14];
  const float* h1_ab   = (const float*)d_in[15];
  const float* W_intw  = (const float*)d_in[16];
  const float* W_sw    = (const float*)d_in[17];
  const float* W_sb    = (const float*)d_in[18];
  const float* pw0     = (const float*)d_in[19];
  const float* pw1     = (const float*)d_in[20];
  const float* pb1     = (const float*)d_in[21];
  float* outp = (float*)d_out;

  float* w = (float*)d_ws;
  float2* ivcu_g = (float2*)w;  w += 2*NP;        // 1MB
  unsigned* hbuf = (unsigned*)w; w += 2*NA*10;    // h pairs, 2 parities
  float* x0g = w;  w += 2*NA;                     // x0, 2 parities
  int* bar   = (int*)w; w += 32;
  bf16* Wmf  = (bf16*)w;                          // 69120 bf16

  k_prep<<<512,256,0,stream>>>(pf,ps,coord,W_intw,W_sw, ivcu_g,Wmf,bar);
  k_all<<<256,512,0,stream>>>(ps, ivcu_g, species, xh, xraw,
                              h0_intw,h0_sw,h0_sb,h0_aw,h0_ab,
                              h1_intw,h1_sw,h1_sb,h1_aw,h1_ab,
                              Wmf, W_sb, pw0, pw1, pb1,
                              hbuf, x0g, outp, bar);
}

// Round 11
// 127.327 us; speedup vs baseline: 1.8365x; 1.1007x over previous
//
#include <hip/hip_runtime.h>
#include <hip/hip_bf16.h>

// Round 11: round-10 design + barrier cacheline fix.
//  - Diagnosis: 11->6 barriers gave exactly 5x18us; per-barrier ~18us was LLC
//    line contention (all 32 molecule counters in ONE 128B line, 256 spinners).
//  - Fix: bar[mol*64] (256B/molecule line) + s_sleep(8) poll backoff.
//  - Everything else verbatim from round-10 (passed, absmax 0.0029).

#define DEG 32
#define NA 4096
#define NP 131072

typedef __hip_bfloat16 bf16;
typedef __attribute__((ext_vector_type(8))) short short8v;
typedef __attribute__((ext_vector_type(4))) float f32x4;

#define Z0F 16.27906976744186f
#define DZ  1.0526315789473684f

__device__ __forceinline__ float frcp(float x){ return __builtin_amdgcn_rcpf(x); }
__device__ __forceinline__ float sigmoid_f(float x){ return frcp(1.f + __expf(-x)); }
__device__ __forceinline__ float tanh_f(float x){ return 1.f - 2.f*frcp(__expf(2.f*x)+1.f); }
__device__ __forceinline__ float softplus_f(float x){ return fmaxf(x,0.f) + __logf(1.f + __expf(-fabsf(x))); }
__device__ __forceinline__ unsigned bf16pack(float lo, float hi){
  unsigned ul = __float_as_uint(lo), uh = __float_as_uint(hi);
  unsigned rl = (ul + 0x7fffu + ((ul>>16)&1u)) >> 16;
  unsigned rh = (uh + 0x7fffu + ((uh>>16)&1u)) & 0xffff0000u;
  return rl | rh;
}
// agent-scope (LLC-coherent, sc1 cache-bypassing) cross-block ld/st
__device__ __forceinline__ unsigned ga_ld(const unsigned* p){
  return __hip_atomic_load(p, __ATOMIC_RELAXED, __HIP_MEMORY_SCOPE_AGENT); }
__device__ __forceinline__ float ga_ldf(const float* p){
  return __hip_atomic_load(p, __ATOMIC_RELAXED, __HIP_MEMORY_SCOPE_AGENT); }
__device__ __forceinline__ void ga_st(unsigned* p, unsigned v){
  __hip_atomic_store(p, v, __ATOMIC_RELAXED, __HIP_MEMORY_SCOPE_AGENT); }
__device__ __forceinline__ void ga_stf(float* p, float v){
  __hip_atomic_store(p, v, __ATOMIC_RELAXED, __HIP_MEMORY_SCOPE_AGENT); }

// fence-free molecule barrier: __syncthreads drains vmcnt(0) per wave, so all
// sc1 stores are at LLC before the relaxed add; readers use sc1 loads.
// barm points at a PRIVATE 256B line per molecule (contention fix).
__device__ __forceinline__ void mol_barrier(int* barm, int target){
  __syncthreads();
  if (threadIdx.x==0){
    __hip_atomic_fetch_add(barm, 1, __ATOMIC_RELAXED, __HIP_MEMORY_SCOPE_AGENT);
    while (__hip_atomic_load(barm, __ATOMIC_RELAXED, __HIP_MEMORY_SCOPE_AGENT) < target)
      __builtin_amdgcn_s_sleep(8);
  }
  __syncthreads();
}

// ---- LDS word offsets (62,112 B) ----
#define P_IVCU 0          // float2[512] own 16 atoms' pairs
#define P_NB   1024       // u8[4096] whole molecule neighbor idx
#define P_XIN  2048       // [128]
#define P_XHP  2176       // u32[128*20] x|h bf16 pairs (x local, h staged)
#define P_C    4736       // [16*20] own c state
#define P_PRJ  5056       // [16]
#define P_PW1  5072       // [20]
#define R0     5096       // overlay arena (10432 w)
#define F_INDF R0         //   f0: 640
#define F_ENV0 (R0+640)   //   f0: 1600
#define F_Y0A  (R0+2240)  //   f0: 640
#define F_Y0B  (R0+2880)  //   f0: 640
#define X_WTS  R0         //   xt: 1700
#define X_EV1  (R0+1700)  //   xt: 2560 (also yB)
#define X_YA   (R0+4260)  //   xt: 2560
#define SVOFF  R0         //   env: sv[16][652]=10432
#define G_ER   R0         //   gemm: u32[16*436]=6976
#define G_TMP  (R0+6976)  //   gemm: 1280
#define G_RED  (R0+8256)  //   lstm: 320
#define G_HT   (R0+8576)  //   lstm: 320
#define SMEMW  (R0+10432) // 15528 words

// ---------------- prep: pair geometry, W->B-frag, barrier init ----------------
__global__ __launch_bounds__(256) void k_prep(
    const int* __restrict__ pf, const int* __restrict__ ps,
    const float* __restrict__ coord,
    const float* __restrict__ Wint, const float* __restrict__ Wself,
    float2* __restrict__ ivcu_g, bf16* __restrict__ Wmf, int* __restrict__ bar)
{
  int tid = blockIdx.x*256 + threadIdx.x;
  if (tid < NP){
    int i = pf[tid], j = ps[tid];
    float dx = coord[i*3+0]-coord[j*3+0];
    float dy = coord[i*3+1]-coord[j*3+1];
    float dz = coord[i*3+2]-coord[j*3+2];
    float d = sqrtf(dx*dx+dy*dy+dz*dz + 1e-12f);
    float cu = 0.f;
    if (d < 7.5f){ float c = __cosf(d * 0.20943951023931953f); cu = c*c; } // pi/15
    ivcu_g[tid] = make_float2(1.f/d, cu);
  }
  if (tid < 69120){
    int j = tid & 7, l = (tid>>3) & 63, gt = (tid>>9)%5, slab = tid/2560;
    int k = slab*32 + ((l>>4)<<3) + j;
    int g = gt*16 + (l&15);
    float v = 0.f;
    if (k < 800)      v = Wint[k*80+g];
    else if (k < 840) v = Wself[(k-800)*80+g];
    Wmf[tid] = __float2bfloat16(v);
  }
  if (tid < 2048) bar[tid] = 0;        // 32 molecules x 64-int (256B) lines
}

// ---------------- the whole recurrence ----------------------------------------
__global__ __launch_bounds__(512) void k_all(
    const int* __restrict__ ps, const float2* __restrict__ ivcu_g,
    const int* __restrict__ species, const float* __restrict__ xh,
    const float* __restrict__ xraw,
    const float* __restrict__ h0_iw, const float* __restrict__ h0_sw,
    const float* __restrict__ h0_sb, const float* __restrict__ h0_aw,
    const float* __restrict__ h0_ab,
    const float* __restrict__ h1_iw, const float* __restrict__ h1_sw,
    const float* __restrict__ h1_sb, const float* __restrict__ h1_aw,
    const float* __restrict__ h1_ab,
    const bf16* __restrict__ Wmf, const float* __restrict__ Wb,
    const float* __restrict__ pw0, const float* __restrict__ pw1,
    const float* __restrict__ pb1,
    unsigned* __restrict__ hbuf,   // [2][NA*10] h bf16-pairs, parity-buffered
    float* __restrict__ x0g,       // [2][NA] x0, parity-buffered
    float* __restrict__ outp, int* __restrict__ bar)
{
  __shared__ float smem[SMEMW];
  const int t = threadIdx.x;
  const int mol = blockIdx.x & 31, sib = blockIdx.x >> 5;  // siblings same XCD
  const int nbase = mol*128;
  const int arow0 = sib*16;
  const int abase = nbase + arow0;
  int* barm = bar + mol*64;            // private 256B line per molecule
  int barno = 0;

  float2* ivcu_s = (float2*)(smem + P_IVCU);
  unsigned char* nb8 = (unsigned char*)(smem + P_NB);
  float* xin_s = smem + P_XIN;
  unsigned* xhp = (unsigned*)(smem + P_XHP);
  float* c_s = smem + P_C;
  float* prj = smem + P_PRJ;
  float* pw1s = smem + P_PW1;

  // ---- prologue: own pairs' ivcu, whole-mol nb8, pw1
  ivcu_s[t] = ivcu_g[abase*DEG + t];
  for(int i=t;i<4096;i+=512) nb8[i] = (unsigned char)(ps[nbase*DEG + i] - nbase);
  if (t < 20) pw1s[t] = pw1[t];

  // ---- f0 (own 16 atoms; indf staged molecule-wide)
  {
    float* indf = smem + F_INDF;
    float* env0 = smem + F_ENV0;
    float* y0a  = smem + F_Y0A;
    float* y0b  = smem + F_Y0B;
    if (t < 128){
      int sp = species[nbase+t];
      indf[t*5+0] = (sp==1)?1.f:0.f;
      indf[t*5+1] = (sp==8)?1.f:0.f;
      indf[t*5+2] = xh[(nbase+t)*3+0];
      indf[t*5+3] = xh[(nbase+t)*3+1];
      indf[t*5+4] = xh[(nbase+t)*3+2];
    }
    __syncthreads();
    if (t < 16){
      int row = arow0 + t;
      prj[t] = pb1[0] + indf[row*5+0]*pw0[0] + indf[row*5+1]*pw0[1]
             + indf[row*5+2]*pw0[2] + indf[row*5+3]*pw0[3] + indf[row*5+4]*pw0[4];
    }
    for(int task=t; task<1600; task+=512){
      int a = task/100, e = task%100, s = e/5, f = e%5;
      const float2* ivr = ivcu_s + a*32;
      const unsigned char* nbr = nb8 + (arow0+a)*32;
      float sz = (float)s*DZ, acc = 0.f;
      for(int k=0;k<32;k++){
        float2 vc = ivr[k];
        float z = (vc.x-0.2f)*Z0F - sz;
        acc += vc.y*__expf(-0.5f*z*z)*indf[nbr[k]*5+f];
      }
      env0[a*100+e] = acc;
    }
    __syncthreads();
    for(int task=t; task<640; task+=512){
      int a=task/40, o=task%40, row=arow0+a;
      float acc = h0_sb[o];
      #pragma unroll
      for(int f=0;f<5;f++) acc += indf[row*5+f]*h0_sw[f*40+o];
      for(int e=0;e<100;e++) acc += env0[a*100+e]*h0_iw[e*40+o];
      y0a[a*40+o] = softplus_f(acc);
    }
    __syncthreads();
    float* cur = y0a; float* nxt = y0b;
    for(int l=0;l<3;l++){
      for(int task=t; task<640; task+=512){
        int a=task/40, o=task%40;
        float acc = h0_ab[l*40+o];
        for(int f=0;f<40;f++) acc += cur[a*40+f]*h0_aw[l*1600+f*40+o];
        nxt[a*40+o] = softplus_f(acc);
      }
      __syncthreads();
      float* tswap=cur; cur=nxt; nxt=tswap;
    }
    // result in y0b (chain y0a->y0b->y0a->y0b)
    if (t < 320){ int a=t/20,u=t%20; c_s[a*20+u] = y0b[a*40+u]; }
    if (t < 160){ int a=t/10,p=t%10;
      ga_st(&hbuf[NA*10 + (abase+a)*10+p],          // parity 1 (pre-step-0)
            bf16pack(y0b[a*40+20+2*p], y0b[a*40+21+2*p])); }
  }
  mol_barrier(barm, 8*(++barno));

  // ---- 5 recurrence steps, 1 barrier each (last skipped)
  for(int step=0; step<5; ++step){
    int use_raw = (step<2)?1:0, col = (step<2)? step : 0;
    int out_col = (step>=2)? (step-2) : -1;
    int rpar = (step+1)&1, wpar = step&1;
    float* wts = smem + X_WTS;
    float* env1 = smem + X_EV1;
    float* yA = smem + X_YA;

    // stage xt weights, xin (whole molecule), h-half of xhp (prev parity)
    for(int i=t;i<1700;i+=512){
      float v;
      if(i<400){ int o=i/20,s=i%20; v=h1_iw[s*20+o]; }
      else if(i<420) v=h1_sw[i-400];
      else if(i<440) v=h1_sb[i-420];
      else if(i<1640){ int q=i-440,l=q/400,rem=q%400,o=rem/20,f=rem%20; v=h1_aw[l*400+f*20+o]; }
      else v=h1_ab[i-1640];
      wts[i]=v;
    }
    if (t < 128)
      xin_s[t] = use_raw ? xraw[(nbase+t)*2+col] : ga_ldf(&x0g[rpar*NA + nbase + t]);
    for(int i=t;i<1280;i+=512)
      xhp[(i/10)*20 + 10 + (i%10)] = ga_ld(&hbuf[rpar*NA*10 + nbase*10 + i]);
    __syncthreads();

    // xt env1 for all 128 molecule atoms (r7-verified): thread=(r,s0), 5 s each
    {
      int r = t & 127, s0 = t >> 7;
      const float2* ivr = ivcu_g + (nbase + r)*DEG;
      const unsigned char* nbr = nb8 + r*32;
      float acc[5] = {0.f,0.f,0.f,0.f,0.f};
      for(int k=0;k<32;k++){
        float2 vc = ivr[k];
        float xv = xin_s[nbr[k]] * vc.y;
        float z0 = (vc.x-0.2f)*Z0F - (float)s0*DZ;
        #pragma unroll
        for(int i=0;i<5;i++){
          float z = z0 - (float)(4*i)*DZ;
          acc[i] += __expf(-0.5f*z*z) * xv;
        }
      }
      #pragma unroll
      for(int i=0;i<5;i++) env1[r*20 + s0 + 4*i] = acc[i];
    }
    __syncthreads();

    // xt interact (env1 -> yA)
    {
      int r = t&127, o0 = t>>7;
      float e[20];
      { const float4* e4=(const float4*)(env1 + r*20);
        float4 q0=e4[0],q1=e4[1],q2=e4[2],q3=e4[3],q4=e4[4];
        e[0]=q0.x;e[1]=q0.y;e[2]=q0.z;e[3]=q0.w; e[4]=q1.x;e[5]=q1.y;e[6]=q1.z;e[7]=q1.w;
        e[8]=q2.x;e[9]=q2.y;e[10]=q2.z;e[11]=q2.w; e[12]=q3.x;e[13]=q3.y;e[14]=q3.z;e[15]=q3.w;
        e[16]=q4.x;e[17]=q4.y;e[18]=q4.z;e[19]=q4.w; }
      float xr_ = xin_s[r];
      #pragma unroll
      for(int i=0;i<5;i++){
        int o = o0 + 4*i;
        const float* w = wts + o*20;
        float acc = wts[420+o] + xr_*wts[400+o];
        #pragma unroll
        for(int f=0;f<20;f++) acc += e[f]*w[f];
        yA[r*20+o] = softplus_f(acc);
      }
    }
    __syncthreads();

    // layers L0 (yA->env1), L1 (env1->yA)
    #pragma unroll
    for(int L=0;L<2;L++){
      const float* src = (L==0)? yA : env1;
      float* dst       = (L==0)? env1 : yA;
      int r = t&127, o0 = t>>7;
      float e[20];
      { const float4* e4=(const float4*)(src + r*20);
        float4 q0=e4[0],q1=e4[1],q2=e4[2],q3=e4[3],q4=e4[4];
        e[0]=q0.x;e[1]=q0.y;e[2]=q0.z;e[3]=q0.w; e[4]=q1.x;e[5]=q1.y;e[6]=q1.z;e[7]=q1.w;
        e[8]=q2.x;e[9]=q2.y;e[10]=q2.z;e[11]=q2.w; e[12]=q3.x;e[13]=q3.y;e[14]=q3.z;e[15]=q3.w;
        e[16]=q4.x;e[17]=q4.y;e[18]=q4.z;e[19]=q4.w; }
      #pragma unroll
      for(int i=0;i<5;i++){
        int o = o0 + 4*i;
        const float* w = wts + 440 + L*400 + o*20;
        float acc = wts[1640 + L*20 + o];
        #pragma unroll
        for(int f=0;f<20;f++) acc += e[f]*w[f];
        dst[r*20+o] = softplus_f(acc);
      }
      __syncthreads();
    }

    // layer L2 (yA -> xhp x-half, bf16 pairs; x never leaves LDS)
    for(int i=t;i<1280;i+=512){
      int r=i/10, p=i%10;
      float e[20];
      { const float4* e4=(const float4*)(yA + r*20);
        float4 q0=e4[0],q1=e4[1],q2=e4[2],q3=e4[3],q4=e4[4];
        e[0]=q0.x;e[1]=q0.y;e[2]=q0.z;e[3]=q0.w; e[4]=q1.x;e[5]=q1.y;e[6]=q1.z;e[7]=q1.w;
        e[8]=q2.x;e[9]=q2.y;e[10]=q2.z;e[11]=q2.w; e[12]=q3.x;e[13]=q3.y;e[14]=q3.z;e[15]=q3.w;
        e[16]=q4.x;e[17]=q4.y;e[18]=q4.z;e[19]=q4.w; }
      int oA=2*p, oB=2*p+1;
      const float* wA = wts + 1240 + oA*20;   // 440 + 2*400
      const float* wB = wA + 20;
      float a0 = wts[1680+oA], a1 = wts[1680+oB];
      #pragma unroll
      for(int f=0;f<20;f++){ a0 += e[f]*wA[f]; a1 += e[f]*wB[f]; }
      xhp[r*20+p] = bf16pack(softplus_f(a0), softplus_f(a1));
    }
    __syncthreads();

    // sv tile (own 16 atoms); arena: wts/env1/yA now dead
    {
      float* sv = smem + SVOFF;
      int a = t>>5, k = t&31;
      float2 vc = ivcu_s[a*32+k];
      float z = (vc.x-0.2f)*Z0F, cu = vc.y;
      float* svr = sv + a*652 + k*20;
      #pragma unroll
      for(int s=0;s<20;s++){ svr[s] = cu*__expf(-0.5f*z*z); z -= DZ; }
    }
    __syncthreads();

    // env accumulate (a,f2)
    float accE[20][2]; unsigned selfp = 0;
    if (t < 320){
      int a=t/20, f2=t%20;
      #pragma unroll
      for(int s=0;s<20;s++){ accE[s][0]=0.f; accE[s][1]=0.f; }
      const float* svr = smem + SVOFF + a*652;
      const unsigned char* nbr = nb8 + (arow0+a)*32;
      for(int k=0;k<32;k++){
        unsigned xp = xhp[nbr[k]*20 + f2];
        float xlo = __uint_as_float(xp<<16);
        float xhi = __uint_as_float(xp & 0xffff0000u);
        const float4* sq = (const float4*)(svr + k*20);
        float4 q0=sq[0],q1=sq[1],q2=sq[2],q3=sq[3],q4=sq[4];
        float sv[20]={q0.x,q0.y,q0.z,q0.w, q1.x,q1.y,q1.z,q1.w,
                      q2.x,q2.y,q2.z,q2.w, q3.x,q3.y,q3.z,q3.w,
                      q4.x,q4.y,q4.z,q4.w};
        #pragma unroll
        for(int s=0;s<20;s++){ accE[s][0] += sv[s]*xlo; accE[s][1] += sv[s]*xhi; }
      }
      selfp = xhp[(arow0+a)*20 + f2];
    }
    __syncthreads();        // sv dead; er overlays
    unsigned* er = (unsigned*)(smem + G_ER);
    if (t < 320){
      int a=t/20, f2=t%20;
      unsigned* e = er + a*436;
      #pragma unroll
      for(int s=0;s<20;s++) e[s*20+f2] = bf16pack(accE[s][0], accE[s][1]);
      e[400+f2] = selfp;
    }
    if (t < 256) er[(t>>4)*436 + 420 + (t&15)] = 0u;
    __syncthreads();

    // MFMA GEMM K=864 (verified r4-r10)
    float* tmp_s = smem + G_TMP;
    if (t < 320){
      int wv = t >> 6, l = t & 63;
      f32x4 cacc = {0.f,0.f,0.f,0.f};
      const unsigned* abase_p = er + (l & 15)*436 + ((l>>4)<<2);
      const short8v* bptr = (const short8v*)Wmf + (wv*64 + l);
      #pragma unroll 3
      for(int slab=0; slab<27; ++slab){
        short8v av = *(const short8v*)(abase_p + slab*16);
        short8v bv = bptr[slab*320];
        cacc = __builtin_amdgcn_mfma_f32_16x16x32_bf16(av, bv, cacc, 0,0,0);
      }
      int g = wv*16 + (l & 15);
      float wb = Wb[g];
      int r0 = (l>>4)*4;
      #pragma unroll
      for(int r=0;r<4;r++) tmp_s[(r0+r)*80 + g] = cacc[r] + wb;
    }
    __syncthreads();

    // LSTM + h/x0 writes (parity wpar)
    float* red = smem + G_RED;
    float* ht  = smem + G_HT;
    if (t < 320){
      int a=t/20, u=t%20;
      float4 tv = *(const float4*)(tmp_s + a*80 + u*4);
      float cold = c_s[a*20+u];
      float cnew = sigmoid_f(tv.y)*cold + sigmoid_f(tv.x)*tanh_f(tv.z);
      float og   = sigmoid_f(tv.w);
      c_s[a*20+u] = cnew;
      ht[a*20+u]  = og*tanh_f(cnew);
      red[a*20+u] = og*pw1s[u];
    }
    __syncthreads();
    if (t < 160){
      int a=t/10, p=t%10;
      ga_st(&hbuf[wpar*NA*10 + (abase+a)*10+p],
            bf16pack(ht[a*20+2*p], ht[a*20+2*p+1]));
    }
    if (t < 16){
      float accx = prj[t];
      #pragma unroll
      for(int u=0;u<20;u++) accx += red[t*20+u];
      ga_stf(&x0g[wpar*NA + abase + t], accx);
      if (out_col >= 0) outp[(abase+t)*3+out_col] = accx;
    }
    if (step < 4) mol_barrier(barm, 8*(++barno));
  }
}

extern "C" void kernel_launch(void* const* d_in, const int* in_sizes, int n_in,
                              void* d_out, int out_size, void* d_ws, size_t ws_size,
                              hipStream_t stream)
{
  const int*   species = (const int*)  d_in[0];
  const float* coord   = (const float*)d_in[1];
  const float* xh      = (const float*)d_in[2];
  const float* xraw    = (const float*)d_in[3];
  const int*   pf      = (const int*)  d_in[4];
  const int*   ps      = (const int*)  d_in[5];
  const float* h0_intw = (const float*)d_in[6];
  const float* h0_sw   = (const float*)d_in[7];
  const float* h0_sb   = (const float*)d_in[8];
  const float* h0_aw   = (const float*)d_in[9];
  const float* h0_ab   = (const float*)d_in[10];
  const float* h1_intw = (const float*)d_in[11];
  const float* h1_sw   = (const float*)d_in[12];
  const float* h1_sb   = (const float*)d_in[13];
  const float* h1_aw   = (const float*)d_in[14];
  const float* h1_ab   = (const float*)d_in[15];
  const float* W_intw  = (const float*)d_in[16];
  const float* W_sw    = (const float*)d_in[17];
  const float* W_sb    = (const float*)d_in[18];
  const float* pw0     = (const float*)d_in[19];
  const float* pw1     = (const float*)d_in[20];
  const float* pb1     = (const float*)d_in[21];
  float* outp = (float*)d_out;

  float* w = (float*)d_ws;
  float2* ivcu_g = (float2*)w;  w += 2*NP;        // 1MB
  unsigned* hbuf = (unsigned*)w; w += 2*NA*10;    // h pairs, 2 parities
  float* x0g = w;  w += 2*NA;                     // x0, 2 parities
  int* bar   = (int*)w; w += 2048;                // 32 molecules x 256B lines
  bf16* Wmf  = (bf16*)w;                          // 69120 bf16

  k_prep<<<512,256,0,stream>>>(pf,ps,coord,W_intw,W_sw, ivcu_g,Wmf,bar);
  k_all<<<256,512,0,stream>>>(ps, ivcu_g, species, xh, xraw,
                              h0_intw,h0_sw,h0_sb,h0_aw,h0_ab,
                              h1_intw,h1_sw,h1_sb,h1_aw,h1_ab,
                              Wmf, W_sb, pw0, pw1, pb1,
                              hbuf, x0g, outp, bar);
}